// Round 1
// baseline (1271.652 us; speedup 1.0000x reference)
//
#include <hip/hip_runtime.h>

// Causal self-attention, B=2 S=2048 D=2048 H=16 DK=128.
// d_out = [out: 4096*2048 f32][attn: 2*16*2048*2048 f32]
// ws    = qb, kb (bf16 [B,H,S,DK]), vT (bf16 [B,H,DK,S]), xb (bf16 [B,S,D]) = 67 MB

#define BATCH 2
#define S_LEN 2048
#define D_DIM 2048
#define H_NUM 16
#define DKD   128

typedef __attribute__((ext_vector_type(8))) short  short8;   // 8 bf16 = 4 VGPR
typedef __attribute__((ext_vector_type(4))) short  short4v;  // 4 bf16 = 8 B
typedef __attribute__((ext_vector_type(4))) float  floatx4;

__device__ __forceinline__ unsigned short f2bf(float f) {
    unsigned int u = __float_as_uint(f);
    u += 0x7fffu + ((u >> 16) & 1u);   // round-to-nearest-even
    return (unsigned short)(u >> 16);
}

// Stage a 128(row) x 32(k) tile into LDS as bf16. src row-major, ld = row stride.
template<typename T>
__device__ __forceinline__ void stage_tile(const T* __restrict__ src, int ld,
                                           int row0, int k0,
                                           unsigned short* __restrict__ dst,
                                           int tid) {
    if constexpr (sizeof(T) == 4) {     // fp32 source: convert
        #pragma unroll
        for (int i = 0; i < 4; ++i) {
            int c = tid + i * 256;          // 1024 chunks of 4 floats
            int r = c >> 3, kc = (c & 7) * 4;
            floatx4 v = *(const floatx4*)(src + (size_t)(row0 + r) * ld + k0 + kc);
            short4v p;
            p[0] = (short)f2bf(v[0]); p[1] = (short)f2bf(v[1]);
            p[2] = (short)f2bf(v[2]); p[3] = (short)f2bf(v[3]);
            *(short4v*)(dst + r * 32 + kc) = p;
        }
    } else {                            // bf16 source: straight copy
        #pragma unroll
        for (int i = 0; i < 2; ++i) {
            int c = tid + i * 256;          // 512 chunks of 8 bf16
            int r = c >> 2, kc = (c & 3) * 8;
            *(short8*)(dst + r * 32 + kc) =
                *(const short8*)(src + (size_t)(row0 + r) * ld + k0 + kc);
        }
    }
}

enum { M_PROJ_QK = 0, M_PROJ_V = 1, M_SCORES = 2, M_PV = 3, M_OUT = 4 };

// C = A @ B^T (+bias) (*scale). A:[M,K] ld=lda, B:[N,K] ld=ldb, row-major.
// 128x128 tile per 256-thread block, 4 waves each 64x64 via 4x4 mfma 16x16x32 bf16.
template<int MODE, typename TA, typename TB>
__launch_bounds__(256)
__global__ void gemm_abt(const TA* __restrict__ Ag, const TB* __restrict__ Bg,
                         const float* __restrict__ bias, void* __restrict__ Cg,
                         int K, int lda, int ldb, float scale) {
    const int m0 = blockIdx.y * 128;
    const int n0 = blockIdx.x * 128;
    int kEnd = K;
    const TA* Ap = Ag;
    const TB* Bp = Bg;

    if constexpr (MODE == M_SCORES) {
        if (n0 > m0 + 127) return;      // tile fully above causal diagonal
        const size_t z = blockIdx.z;
        Ap = Ag + z * (size_t)S_LEN * DKD;
        Bp = Bg + z * (size_t)S_LEN * DKD;
    }
    if constexpr (MODE == M_PV) {
        const size_t z = blockIdx.z;
        Ap = Ag + z * (size_t)S_LEN * S_LEN;
        Bp = Bg + z * (size_t)DKD * S_LEN;
        kEnd = m0 + 128;                // attn[m,k]==0 for k>m
    }

    __shared__ __align__(16) unsigned short As[128][32];
    __shared__ __align__(16) unsigned short Bs[128][32];

    const int tid  = threadIdx.x;
    const int lane = tid & 63;
    const int wave = tid >> 6;
    const int quad = lane >> 4;
    const int l16  = lane & 15;
    const int mw   = (wave >> 1) * 64;
    const int nw   = (wave & 1) * 64;

    floatx4 acc[4][4];
    #pragma unroll
    for (int i = 0; i < 4; ++i)
        #pragma unroll
        for (int j = 0; j < 4; ++j)
            acc[i][j] = (floatx4){0.f, 0.f, 0.f, 0.f};

    for (int k0 = 0; k0 < kEnd; k0 += 32) {
        if (k0 > 0) __syncthreads();
        stage_tile<TA>(Ap, lda, m0, k0, &As[0][0], tid);
        stage_tile<TB>(Bp, ldb, n0, k0, &Bs[0][0], tid);
        __syncthreads();

        short8 af[4], bf[4];
        #pragma unroll
        for (int i = 0; i < 4; ++i)
            af[i] = *(const short8*)&As[mw + i * 16 + l16][quad * 8];
        #pragma unroll
        for (int j = 0; j < 4; ++j)
            bf[j] = *(const short8*)&Bs[nw + j * 16 + l16][quad * 8];
        #pragma unroll
        for (int i = 0; i < 4; ++i)
            #pragma unroll
            for (int j = 0; j < 4; ++j)
                acc[i][j] = __builtin_amdgcn_mfma_f32_16x16x32_bf16(
                    af[i], bf[j], acc[i][j], 0, 0, 0);
    }

    // Epilogue: C/D layout col = lane&15, row = quad*4 + reg  [verified m89/m91]
    #pragma unroll
    for (int i = 0; i < 4; ++i) {
        #pragma unroll
        for (int j = 0; j < 4; ++j) {
            #pragma unroll
            for (int r = 0; r < 4; ++r) {
                const int row = m0 + mw + i * 16 + quad * 4 + r;
                const int col = n0 + nw + j * 16 + l16;
                float v = acc[i][j][r];
                if constexpr (MODE == M_PROJ_QK || MODE == M_PROJ_V) {
                    v += bias[col];
                    const int b = row >> 11, s = row & (S_LEN - 1);
                    const int h = col >> 7,  dk = col & (DKD - 1);
                    unsigned short* o = (unsigned short*)Cg;
                    if constexpr (MODE == M_PROJ_QK)
                        o[((size_t)(b * H_NUM + h) * S_LEN + s) * DKD + dk] = f2bf(v);
                    else
                        o[((size_t)(b * H_NUM + h) * DKD + dk) * S_LEN + s] = f2bf(v);
                } else if constexpr (MODE == M_SCORES) {
                    float* o = (float*)Cg + (size_t)blockIdx.z * S_LEN * S_LEN;
                    o[(size_t)row * S_LEN + col] = v * scale;
                } else if constexpr (MODE == M_PV) {
                    const int z = blockIdx.z, b = z >> 4, h = z & 15;
                    unsigned short* o = (unsigned short*)Cg;
                    o[((size_t)(b * S_LEN + row)) * D_DIM + h * DKD + col] = f2bf(v);
                } else {  // M_OUT
                    float* o = (float*)Cg;
                    o[(size_t)row * D_DIM + col] = v + bias[col];
                }
            }
        }
    }
}

// Causal softmax in place over attn [B*H, S, S]; one wave per row.
// Masked cols (> row) written as exact 0.0 (ref: exp(-1e9 - max) underflows).
__launch_bounds__(256)
__global__ void softmax_causal(float* __restrict__ attn) {
    const int lane = threadIdx.x & 63;
    const int wave = threadIdx.x >> 6;
    const int s = blockIdx.x * 4 + wave;       // row
    float* rowp = attn + ((size_t)blockIdx.y * S_LEN + s) * S_LEN;

    float vals[32];
    float mx = -3.0e38f;
    #pragma unroll
    for (int j = 0; j < 32; ++j) {
        const int idx = lane + j * 64;
        const float v = (idx <= s) ? rowp[idx] : -3.0e38f;
        vals[j] = v;
        mx = fmaxf(mx, v);
    }
    #pragma unroll
    for (int off = 32; off; off >>= 1) mx = fmaxf(mx, __shfl_down(mx, off, 64));
    mx = __shfl(mx, 0, 64);

    float sum = 0.f;
    #pragma unroll
    for (int j = 0; j < 32; ++j) {
        const int idx = lane + j * 64;
        const float e = (idx <= s) ? __expf(vals[j] - mx) : 0.f;
        vals[j] = e;
        sum += e;
    }
    #pragma unroll
    for (int off = 32; off; off >>= 1) sum += __shfl_down(sum, off, 64);
    sum = __shfl(sum, 0, 64);

    const float inv = 1.f / sum;
    #pragma unroll
    for (int j = 0; j < 32; ++j) rowp[lane + j * 64] = vals[j] * inv;
}

extern "C" void kernel_launch(void* const* d_in, const int* in_sizes, int n_in,
                              void* d_out, int out_size, void* d_ws, size_t ws_size,
                              hipStream_t stream) {
    const float* query = (const float*)d_in[0];
    const float* key_  = (const float*)d_in[1];
    const float* value = (const float*)d_in[2];
    const float* Wq = (const float*)d_in[3];
    const float* bq = (const float*)d_in[4];
    const float* Wk = (const float*)d_in[5];
    const float* bk = (const float*)d_in[6];
    const float* Wv = (const float*)d_in[7];
    const float* bv = (const float*)d_in[8];
    const float* Wo = (const float*)d_in[9];
    const float* bo = (const float*)d_in[10];

    float* out  = (float*)d_out;
    float* attn = out + (size_t)BATCH * S_LEN * D_DIM;

    const size_t NE = (size_t)BATCH * S_LEN * D_DIM;   // 8388608
    unsigned short* qb = (unsigned short*)d_ws;
    unsigned short* kb = qb + NE;
    unsigned short* vT = kb + NE;
    unsigned short* xb = vT + NE;

    const dim3 blk(256);
    const float iscale = 0.088388347648318447f;        // 1/sqrt(128)

    // QKV projections: [4096,2048] @ [2048,2048]^T
    const dim3 gproj(D_DIM / 128, (BATCH * S_LEN) / 128, 1);
    gemm_abt<M_PROJ_QK, float, float><<<gproj, blk, 0, stream>>>(
        query, Wq, bq, qb, D_DIM, D_DIM, D_DIM, 1.f);
    gemm_abt<M_PROJ_QK, float, float><<<gproj, blk, 0, stream>>>(
        key_, Wk, bk, kb, D_DIM, D_DIM, D_DIM, 1.f);
    gemm_abt<M_PROJ_V, float, float><<<gproj, blk, 0, stream>>>(
        value, Wv, bv, vT, D_DIM, D_DIM, D_DIM, 1.f);

    // Scores: per (b,h)  q[S,DK] @ k[S,DK]^T * 1/sqrt(DK), causal tiles only
    const dim3 gsc(S_LEN / 128, S_LEN / 128, BATCH * H_NUM);
    gemm_abt<M_SCORES, unsigned short, unsigned short><<<gsc, blk, 0, stream>>>(
        qb, kb, nullptr, attn, DKD, DKD, DKD, iscale);

    // Causal softmax in place
    softmax_causal<<<dim3(S_LEN / 4, BATCH * H_NUM), blk, 0, stream>>>(attn);

    // PV: per (b,h)  attn[S,S] @ vT[DK,S]^T, K limited to m0+128
    const dim3 gpv(1, S_LEN / 128, BATCH * H_NUM);
    gemm_abt<M_PV, float, unsigned short><<<gpv, blk, 0, stream>>>(
        attn, vT, nullptr, xb, S_LEN, S_LEN, S_LEN, 1.f);

    // Output projection: x[4096,2048] @ Wo^T + bo -> fp32 out
    const dim3 gout(D_DIM / 128, (BATCH * S_LEN) / 128, 1);
    gemm_abt<M_OUT, unsigned short, float><<<gout, blk, 0, stream>>>(
        xb, Wo, bo, out, D_DIM, D_DIM, D_DIM, 1.f);
}